// Round 3
// baseline (151.310 us; speedup 1.0000x reference)
//
#include <hip/hip_runtime.h>
#include <stdint.h>

// GraphConvolution: out = D^-1 (A+I) (X W) + b
// R3: adj streamed with 512B-contiguous per-row segments -> LDS (XOR-swizzled)
// -> 32x32x16 bf16 MFMA. Full-K per block (grid 256 = 1/CU): rowsum, D^-1,
// +I and bias fused in k_spmm; partial buffers and k_final eliminated.
// Raw s_barrier + lgkmcnt-only waits keep global loads in flight (T3/T4).

#define NROW 8192
#define FIN 256
#define FOUT 128
#define SK 64          // K per stage
#define NST (NROW / SK)  // 128 stages

typedef __attribute__((ext_vector_type(8))) short bf16x8;
typedef __attribute__((ext_vector_type(16))) float f32x16;

static __device__ __forceinline__ unsigned short f2bf(float x) {
  unsigned u = __builtin_bit_cast(unsigned, x);
  u = (u + 0x7FFFu + ((u >> 16) & 1u)) >> 16;
  return (unsigned short)u;
}

// ---------------- Kernel 1: support = X @ W (f32) + bf16 transposed copy ----
__global__ __launch_bounds__(256) void k_support(
    const float* __restrict__ input, const float* __restrict__ weight,
    float* __restrict__ support, unsigned short* __restrict__ supportT) {
  __shared__ __align__(16) float in_lds[16 * FIN];
  __shared__ __align__(16) float tr_lds[16 * (FOUT + 4)];
  const int t = threadIdx.x;
  const int rbase = blockIdx.x * 16;
  const float* src = input + (size_t)rbase * FIN;
#pragma unroll
  for (int c = 0; c < 4; ++c) {
    const int idx = c * 1024 + t * 4;
    *(float4*)&in_lds[idx] = *(const float4*)&src[idx];
  }
  __syncthreads();
  const int j = t & 127;
  const int rg = t >> 7;
  float acc[8] = {0.f, 0.f, 0.f, 0.f, 0.f, 0.f, 0.f, 0.f};
  for (int f = 0; f < FIN; f += 4) {
    const float w0 = weight[(f + 0) * FOUT + j];
    const float w1 = weight[(f + 1) * FOUT + j];
    const float w2 = weight[(f + 2) * FOUT + j];
    const float w3 = weight[(f + 3) * FOUT + j];
#pragma unroll
    for (int r = 0; r < 8; ++r) {
      const float4 iv = *(const float4*)&in_lds[(rg * 8 + r) * FIN + f];
      acc[r] += iv.x * w0 + iv.y * w1 + iv.z * w2 + iv.w * w3;
    }
  }
#pragma unroll
  for (int r = 0; r < 8; ++r) {
    const int row = rbase + rg * 8 + r;
    support[(size_t)row * FOUT + j] = acc[r];
    tr_lds[(rg * 8 + r) * (FOUT + 4) + j] = acc[r];
  }
  __syncthreads();
  const int r = t & 15, g = t >> 4;
#pragma unroll
  for (int jj = 0; jj < 8; ++jj) {
    const int jc = jj * 16 + g;
    supportT[(size_t)jc * NROW + rbase + r] = f2bf(tr_lds[r * (FOUT + 4) + jc]);
  }
}

// ---------------- Kernel 2 (fused): out = D^-1 (A @ S + S) + b --------------
// Block: 32 rows x 128 cols, full K. 512 thr = 8 waves: cg=w>>1 (32-col
// quadrant), kw=w&1 (k-half of each stage). LDS: A dbuf 2x4KB + B dbuf 2x16KB
// + rowsum 128B; epilogue merge buffer aliases the staging region.
__global__ __launch_bounds__(512, 2) void k_spmm(
    const float* __restrict__ adj, const unsigned short* __restrict__ supportT,
    const float* __restrict__ support, const float* __restrict__ bias,
    float* __restrict__ out) {
  __shared__ __align__(16) unsigned char LDS[41088];
  const int t = threadIdx.x;
  const int l = t & 63, w = t >> 6;
  const int cg = w >> 1, kw = w & 1;
  const int l31 = l & 31, kg = l >> 5;
  const int rbase = blockIdx.x * 32;

  // A staging: thread (sr, sc) reads adj[rbase+sr][s*64 + sc*4 .. +4] — each
  // row's stage slice is 256B contiguous, wave covers 4 rows x 512B... per-row
  // contiguous 256B segments, consecutive threads consecutive addresses.
  const int sr = t >> 4, sc = t & 15;
  const float* aG = adj + (size_t)(rbase + sr) * NROW + sc * 4;
  const int aL = sr * 128 + ((((sc >> 1)) ^ (sr & 7)) << 4) + (sc & 1) * 8;
  // B staging: thread (bcol, bj) reads supportT[bcol][s*64 + bj*16 .. +16]
  const int bcol = t >> 2, bj = t & 3;
  const unsigned short* bG = supportT + (size_t)bcol * NROW + bj * 16;
  const int bL0 = 8192 + bcol * 128 + (((bj * 2) ^ (bcol & 7)) << 4);
  const int bL1 = 8192 + bcol * 128 + (((bj * 2 + 1) ^ (bcol & 7)) << 4);

  // fragment read offsets (unit = 16B = 8 bf16 of k); u = kw*4 + ks2*2 + kg
  const int u0 = kw * 4 + kg;
  const int aF0 = l31 * 128 + ((u0 ^ (l31 & 7)) << 4);
  const int aF1 = l31 * 128 + (((u0 + 2) ^ (l31 & 7)) << 4);
  const int colg = cg * 32 + l31;
  const int bF0 = 8192 + colg * 128 + ((u0 ^ (colg & 7)) << 4);
  const int bF1 = 8192 + colg * 128 + (((u0 + 2) ^ (colg & 7)) << 4);

  struct Stage { float4 a; uint4 b0, b1; };
  Stage S0, S1;
  float rs = 0.f;
  f32x16 acc;
#pragma unroll
  for (int q = 0; q < 16; ++q) acc[q] = 0.f;

  auto load_stage = [&](Stage& S, int s) {
    S.a = *(const float4*)(aG + s * SK);
    S.b0 = *(const uint4*)(bG + (size_t)s * SK);
    S.b1 = *(const uint4*)(bG + (size_t)s * SK + 8);
  };
  auto store_stage = [&](const Stage& S, int buf) {
    rs += (S.a.x + S.a.y) + (S.a.z + S.a.w);
    uint2 p;
    asm("v_cvt_pk_bf16_f32 %0, %1, %2" : "=v"(p.x) : "v"(S.a.x), "v"(S.a.y));
    asm("v_cvt_pk_bf16_f32 %0, %1, %2" : "=v"(p.y) : "v"(S.a.z), "v"(S.a.w));
    *(uint2*)(LDS + buf * 4096 + aL) = p;
    *(uint4*)(LDS + buf * 16384 + bL0) = S.b0;
    *(uint4*)(LDS + buf * 16384 + bL1) = S.b1;
  };
  auto compute = [&](int buf) {
    const bf16x8 a0 = *(const bf16x8*)(LDS + buf * 4096 + aF0);
    const bf16x8 b0 = *(const bf16x8*)(LDS + buf * 16384 + bF0);
    const bf16x8 a1 = *(const bf16x8*)(LDS + buf * 4096 + aF1);
    const bf16x8 b1 = *(const bf16x8*)(LDS + buf * 16384 + bF1);
    acc = __builtin_amdgcn_mfma_f32_32x32x16_bf16(a0, b0, acc, 0, 0, 0);
    acc = __builtin_amdgcn_mfma_f32_32x32x16_bf16(a1, b1, acc, 0, 0, 0);
  };

  // prologue: stages 0,1,2 issued; stage 0 staged into buf0
  load_stage(S0, 0);
  load_stage(S1, 1);
  store_stage(S0, 0);  // compiler inserts counted vmcnt for S0 only
  load_stage(S0, 2);
  asm volatile("s_waitcnt lgkmcnt(0)" ::: "memory");
  __builtin_amdgcn_s_barrier();

  for (int s = 0; s < NST; ++s) {
    const int buf = s & 1;
    compute(buf);
    if (s + 1 < NST) {
      if (buf == 0) {
        store_stage(S1, 1);
        if (s + 3 < NST) load_stage(S1, s + 3);
      } else {
        store_stage(S0, 0);
        if (s + 3 < NST) load_stage(S0, s + 3);
      }
    }
    asm volatile("s_waitcnt lgkmcnt(0)" ::: "memory");
    __builtin_amdgcn_s_barrier();
  }

  // rowsum: thread covers row sr over its k-slice; lanes differing in bits
  // 0..3 (sc) share the row -> shuffle-reduce, one writer per row.
  rs += __shfl_xor(rs, 1, 64);
  rs += __shfl_xor(rs, 2, 64);
  rs += __shfl_xor(rs, 4, 64);
  rs += __shfl_xor(rs, 8, 64);
  if ((l & 15) == 0) *(float*)(LDS + 40960 + (w * 4 + (l >> 4)) * 4) = rs;

  // kw-merge: kw=1 waves park acc in (now-dead) staging LDS, kw=0 combine.
  float* mb = (float*)(LDS + cg * 4096);
  if (kw) {
#pragma unroll
    for (int q = 0; q < 16; ++q) mb[q * 64 + l] = acc[q];
  }
  asm volatile("s_waitcnt lgkmcnt(0)" ::: "memory");
  __builtin_amdgcn_s_barrier();

  if (!kw) {
    // C/D layout (m74/m101): col = lane&31, row = (q&3) + 8*(q>>2) + 4*kg
#pragma unroll
    for (int q = 0; q < 16; ++q) {
      const int row = (q & 3) + 8 * (q >> 2) + 4 * kg;
      const float v = acc[q] + mb[q * 64 + l];
      const float deg = 1.f + *(const float*)(LDS + 40960 + row * 4);
      float dinv = 1.f / deg;
      if (dinv != dinv) dinv = 0.f;
      const size_t o = (size_t)(rbase + row) * FOUT + colg;
      out[o] = (v + support[o]) * dinv + bias[colg];
    }
  }
}

extern "C" void kernel_launch(void* const* d_in, const int* in_sizes, int n_in,
                              void* d_out, int out_size, void* d_ws, size_t ws_size,
                              hipStream_t stream) {
  const float* input  = (const float*)d_in[0];
  const float* adj    = (const float*)d_in[1];
  const float* weight = (const float*)d_in[2];
  const float* bias   = (const float*)d_in[3];
  float* out = (float*)d_out;
  float* ws = (float*)d_ws;
  // ws: support f32 [8192*128] | supportT bf16 [128][8192]  (~6 MB)
  float* support = ws;
  unsigned short* supportT = (unsigned short*)(ws + (size_t)NROW * FOUT);

  k_support<<<NROW / 16, 256, 0, stream>>>(input, weight, support, supportT);
  k_spmm<<<NROW / 32, 512, 0, stream>>>(adj, supportT, support, bias, out);
}